// Round 9
// baseline (297.255 us; speedup 1.0000x reference)
//
#include <hip/hip_runtime.h>
#include <hip/hip_bf16.h>

#define NT 64
#define DM 192

typedef __attribute__((ext_vector_type(4))) float f32x4;
typedef __attribute__((ext_vector_type(4))) float float4v;
using half2v = __attribute__((ext_vector_type(2))) _Float16;
using half4v = __attribute__((ext_vector_type(4))) _Float16;

// ws layout (bytes)
#define BIAS_OFF  147456      // 8*36*512 W-frags
#define TAB_OFF   6438912     // BIAS_OFF + 384*16*64*16
#define SCALE_OFF 6444312

__device__ __forceinline__ half4v pk4(float a, float b, float c, float d){
  half2v lo = __builtin_bit_cast(half2v, __builtin_amdgcn_cvt_pkrtz(a, b));
  half2v hi = __builtin_bit_cast(half2v, __builtin_amdgcn_cvt_pkrtz(c, d));
  half4v r; r[0]=lo[0]; r[1]=lo[1]; r[2]=hi[0]; r[3]=hi[1];
  return r;
}

// ---------------- precompute A: W A-frags (16x16x16 layout) + rpb-mlp table + scales ----------------
// Residual fold: q/k/v weights (mats 0..5) get +I so q = x0*(W+I)^T + b  (p-weights unchanged).
__global__ __launch_bounds__(384) void pre_a(
  const float* __restrict__ q1w, const float* __restrict__ q2w,
  const float* __restrict__ k1w, const float* __restrict__ k2w,
  const float* __restrict__ v1w, const float* __restrict__ v2w,
  const float* __restrict__ p1w, const float* __restrict__ p2w,
  const float* __restrict__ w1, const float* __restrict__ b1,
  const float* __restrict__ w2, const float* __restrict__ rpbt,
  const float* __restrict__ ls, char* __restrict__ ws)
{
  int blk = blockIdx.x, t = threadIdx.x;
  if (blk < 48) {
    const float* Ws[8] = {q1w,q2w,k1w,k2w,v1w,v2w,p1w,p2w};
    int mat = blk / 6, ct = blk % 6;
    int lane = t & 63, ks = t >> 6;        // ks 0..5
    const float* W = Ws[mat];
    int c  = 16*ct + (lane & 15);
    int d0 = 16*ks + 4*(lane >> 4);
    half4v h;
    #pragma unroll
    for (int j = 0; j < 4; ++j) {
      float wel = W[c*96 + d0 + j];
      if (mat < 6 && c == d0 + j) wel += 1.0f;   // fold residual identity
      h[j] = (_Float16)wel;
    }
    *(half4v*)(ws + (size_t)((mat*6+ct)*6+ks)*512 + lane*8) = h;
  } else {
    float* tab = (float*)(ws + TAB_OFF);
    if (t < 225) {
      float t0 = rpbt[2*t], t1 = rpbt[2*t+1];
      float acc[6] = {0,0,0,0,0,0};
      for (int j = 0; j < 128; ++j) {
        float hv = fmaxf(t0*w1[2*j] + t1*w1[2*j+1] + b1[j], 0.f);
        #pragma unroll
        for (int hh = 0; hh < 6; ++hh) acc[hh] += hv * w2[hh*128 + j];
      }
      #pragma unroll
      for (int hh = 0; hh < 6; ++hh) tab[t*6 + hh] = acc[hh];
    }
    if (t >= 240 && t < 246) {
      float* sc = (float*)(ws + SCALE_OFF);
      int i = t - 240;
      sc[i] = expf(fminf(ls[i], 4.605170185988091f)); // log(100)
    }
  }
}

// ---------------- precompute B: bias = 16*sigmoid(rpb)+mask in S^T fragment order ----------------
__global__ __launch_bounds__(256) void pre_b(
  const float* __restrict__ mask, const int* __restrict__ rpi,
  char* __restrict__ ws)
{
  int w = blockIdx.x / 6, h = blockIdx.x % 6;
  int lane = threadIdx.x & 63, nt = threadIdx.x >> 6;
  const float* tab = (const float*)(ws + TAB_OFF);
  float* bias = (float*)(ws + BIAS_OFF);
  #pragma unroll
  for (int mt = 0; mt < 4; ++mt)
    #pragma unroll
    for (int r = 0; r < 4; ++r) {
      int m = 16*mt + ((lane >> 4) << 2) + r;
      int n = 16*nt + (lane & 15);
      int idx = rpi[n*64 + m];
      float tv = tab[idx*6 + h];
      float sg = 16.f / (1.f + expf(-tv));
      float mv = mask[(w*64 + n)*64 + m];
      bias[(size_t)(((w*6+h)*4+mt)*4+nt)*256 + lane*4 + r] = sg + mv;
    }
}

// ---------------- main fused kernel: 1 block = 1 window, 6 waves = 6 heads ----------------
// Transpose-free fragment chaining; residual folded into weights; phases ordered
// Q -> K -> S/softmax -> V -> PV -> proj to minimize peak register coexistence.
// launch_bounds(384,4): total regs/wave <= 128 -> 2 blocks/CU (12 waves, decoupled).
__global__ __launch_bounds__(384, 4) void win_attn(
  const float* __restrict__ x, const char* __restrict__ ws,
  const float* __restrict__ q1b, const float* __restrict__ q2b,
  const float* __restrict__ k1b, const float* __restrict__ k2b,
  const float* __restrict__ v1b, const float* __restrict__ v2b,
  const float* __restrict__ p1b, const float* __restrict__ p2b,
  float* __restrict__ out)
{
  __shared__ __align__(16) _Float16 xo[64*200];   // x (f16), later o overlay
  const int tid = threadIdx.x;
  const int wv = tid >> 6, lane = tid & 63;
  const int llo = lane & 15, lhi = lane >> 4;
  const int b = blockIdx.x, w_in = b & 63;
  const int h = wv;
  const int half = (h < 3) ? 0 : 1;
  const int hd0 = 32 * (h % 3);                   // head-dim base within half
  const f32x4 zf = {0.f,0.f,0.f,0.f};
  const float* xg = x + (size_t)b * (NT*DM);

  // ---- stage x -> LDS f16 ----
  float4v xv[8];
  #pragma unroll
  for (int it = 0; it < 8; ++it) xv[it] = *(const float4v*)(xg + 4*(tid + it*384));
  #pragma unroll
  for (int it = 0; it < 8; ++it) {
    int f4 = tid + it*384;
    int row = f4 / 48, c4 = f4 % 48;
    *(half4v*)(xo + row*200 + c4*4) = pk4(xv[it][0], xv[it][1], xv[it][2], xv[it][3]);
  }
  __syncthreads();   // (1) x staged

  const float scale_h = ((const float*)(ws + SCALE_OFF))[h];

  // ---- Q pass: q^T = Wq' * x^T (+bias), l2norm(+scale) -> qf frags ----
  half4v qf[2][4];
  {
    f32x4 acc[2][4];
    #pragma unroll
    for (int dt = 0; dt < 2; ++dt)
      #pragma unroll
      for (int tt = 0; tt < 4; ++tt) acc[dt][tt] = zf;
    #pragma unroll
    for (int ks = 0; ks < 6; ++ks) {
      half4v xf[4];
      #pragma unroll
      for (int tt = 0; tt < 4; ++tt)
        xf[tt] = *(const half4v*)(xo + (16*tt+llo)*200 + half*96 + 16*ks + 4*lhi);
      #pragma unroll
      for (int dt = 0; dt < 2; ++dt) {
        half4v wq = *(const half4v*)(ws + (size_t)(((0+half)*6 + 2*(h%3)+dt)*6 + ks)*512 + lane*8);
        #pragma unroll
        for (int tt = 0; tt < 4; ++tt)
          acc[dt][tt] = __builtin_amdgcn_mfma_f32_16x16x16f16(wq, xf[tt], acc[dt][tt], 0,0,0);
      }
    }
    const float* qbp = half ? q2b : q1b;
    float4v qb[2];
    #pragma unroll
    for (int dt = 0; dt < 2; ++dt) qb[dt] = *(const float4v*)(qbp + hd0 + 16*dt + 4*lhi);
    #pragma unroll
    for (int tt = 0; tt < 4; ++tt) {
      float qv[2][4];
      float sq = 0.f;
      #pragma unroll
      for (int dt = 0; dt < 2; ++dt)
        #pragma unroll
        for (int r = 0; r < 4; ++r) { qv[dt][r] = acc[dt][tt][r] + qb[dt][r]; sq += qv[dt][r]*qv[dt][r]; }
      sq += __shfl_xor(sq, 16); sq += __shfl_xor(sq, 32);
      float invq = scale_h / fmaxf(sqrtf(sq), 1e-12f);
      #pragma unroll
      for (int dt = 0; dt < 2; ++dt)
        qf[dt][tt] = pk4(qv[dt][0]*invq, qv[dt][1]*invq, qv[dt][2]*invq, qv[dt][3]*invq);
    }
  }

  // ---- K pass: k^T = Wk' * x^T (+bias), l2norm -> kf frags ----
  half4v kf[2][4];
  {
    f32x4 acc[2][4];
    #pragma unroll
    for (int dt = 0; dt < 2; ++dt)
      #pragma unroll
      for (int tt = 0; tt < 4; ++tt) acc[dt][tt] = zf;
    #pragma unroll
    for (int ks = 0; ks < 6; ++ks) {
      half4v xf[4];
      #pragma unroll
      for (int tt = 0; tt < 4; ++tt)
        xf[tt] = *(const half4v*)(xo + (16*tt+llo)*200 + half*96 + 16*ks + 4*lhi);
      #pragma unroll
      for (int dt = 0; dt < 2; ++dt) {
        half4v wk = *(const half4v*)(ws + (size_t)(((2+half)*6 + 2*(h%3)+dt)*6 + ks)*512 + lane*8);
        #pragma unroll
        for (int tt = 0; tt < 4; ++tt)
          acc[dt][tt] = __builtin_amdgcn_mfma_f32_16x16x16f16(wk, xf[tt], acc[dt][tt], 0,0,0);
      }
    }
    const float* kbp = half ? k2b : k1b;
    float4v kb[2];
    #pragma unroll
    for (int dt = 0; dt < 2; ++dt) kb[dt] = *(const float4v*)(kbp + hd0 + 16*dt + 4*lhi);
    #pragma unroll
    for (int tt = 0; tt < 4; ++tt) {
      float kv[2][4];
      float sk = 0.f;
      #pragma unroll
      for (int dt = 0; dt < 2; ++dt)
        #pragma unroll
        for (int r = 0; r < 4; ++r) { kv[dt][r] = acc[dt][tt][r] + kb[dt][r]; sk += kv[dt][r]*kv[dt][r]; }
      sk += __shfl_xor(sk, 16); sk += __shfl_xor(sk, 32);
      float invk = 1.f / fmaxf(sqrtf(sk), 1e-12f);
      #pragma unroll
      for (int dt = 0; dt < 2; ++dt)
        kf[dt][tt] = pk4(kv[dt][0]*invk, kv[dt][1]*invk, kv[dt][2]*invk, kv[dt][3]*invk);
    }
  }

  // ---- S^T = kn * qn^T (+fused bias), softmax over m (in-lane + 2 shfl) -> P^T frags ----
  const float4v* biasf = (const float4v*)(ws + BIAS_OFF);
  half4v pf[4][4];
  #pragma unroll
  for (int nt = 0; nt < 4; ++nt) {
    f32x4 s[4];
    #pragma unroll
    for (int mt = 0; mt < 4; ++mt) {
      f32x4 t0 = __builtin_amdgcn_mfma_f32_16x16x16f16(kf[0][mt], qf[0][nt], zf, 0,0,0);
      s[mt]    = __builtin_amdgcn_mfma_f32_16x16x16f16(kf[1][mt], qf[1][nt], t0, 0,0,0);
      float4v bb = biasf[(size_t)(((w_in*6 + h)*4 + mt)*4 + nt)*64 + lane];
      s[mt][0] += bb[0]; s[mt][1] += bb[1]; s[mt][2] += bb[2]; s[mt][3] += bb[3];
    }
    float mx = s[0][0];
    #pragma unroll
    for (int mt = 0; mt < 4; ++mt)
      #pragma unroll
      for (int r = 0; r < 4; ++r) mx = fmaxf(mx, s[mt][r]);
    mx = fmaxf(mx, __shfl_xor(mx, 16)); mx = fmaxf(mx, __shfl_xor(mx, 32));
    float e[4][4]; float sum = 0.f;
    #pragma unroll
    for (int mt = 0; mt < 4; ++mt)
      #pragma unroll
      for (int r = 0; r < 4; ++r) { e[mt][r] = __expf(s[mt][r] - mx); sum += e[mt][r]; }
    sum += __shfl_xor(sum, 16); sum += __shfl_xor(sum, 32);
    float inv = 1.f / sum;
    #pragma unroll
    for (int mt = 0; mt < 4; ++mt)
      pf[mt][nt] = pk4(e[mt][0]*inv, e[mt][1]*inv, e[mt][2]*inv, e[mt][3]*inv);
  }

  // ---- V pass: v = x * Wv'^T (+bias) -> vf frags (residual folded into Wv') ----
  half4v vf[4][2];
  {
    f32x4 acc[4][2];
    #pragma unroll
    for (int tt = 0; tt < 4; ++tt) { acc[tt][0] = zf; acc[tt][1] = zf; }
    #pragma unroll
    for (int ks = 0; ks < 6; ++ks) {
      half4v xf[4];
      #pragma unroll
      for (int tt = 0; tt < 4; ++tt)
        xf[tt] = *(const half4v*)(xo + (16*tt+llo)*200 + half*96 + 16*ks + 4*lhi);
      #pragma unroll
      for (int ct = 0; ct < 2; ++ct) {
        half4v wvf = *(const half4v*)(ws + (size_t)(((4+half)*6 + 2*(h%3)+ct)*6 + ks)*512 + lane*8);
        #pragma unroll
        for (int tt = 0; tt < 4; ++tt)
          acc[tt][ct] = __builtin_amdgcn_mfma_f32_16x16x16f16(xf[tt], wvf, acc[tt][ct], 0,0,0);
      }
    }
    const float* vbp = half ? v2b : v1b;
    #pragma unroll
    for (int ct = 0; ct < 2; ++ct) {
      float vb = vbp[hd0 + 16*ct + llo];
      #pragma unroll
      for (int tt = 0; tt < 4; ++tt)
        vf[tt][ct] = pk4(acc[tt][ct][0] + vb, acc[tt][ct][1] + vb,
                         acc[tt][ct][2] + vb, acc[tt][ct][3] + vb);
    }
  }

  // ---- o^T = V^T * P^T (all-register) ----
  f32x4 oacc[2][4];
  #pragma unroll
  for (int dt = 0; dt < 2; ++dt)
    #pragma unroll
    for (int nt = 0; nt < 4; ++nt) oacc[dt][nt] = zf;
  #pragma unroll
  for (int mt = 0; mt < 4; ++mt)
    #pragma unroll
    for (int dt = 0; dt < 2; ++dt)
      #pragma unroll
      for (int nt = 0; nt < 4; ++nt)
        oacc[dt][nt] = __builtin_amdgcn_mfma_f32_16x16x16f16(vf[mt][dt], pf[mt][nt], oacc[dt][nt], 0,0,0);

  __syncthreads();   // (2) all waves done reading x
  #pragma unroll
  for (int dt = 0; dt < 2; ++dt)
    #pragma unroll
    for (int nt = 0; nt < 4; ++nt)
      *(half4v*)(xo + (16*nt+llo)*200 + 32*h + 16*dt + 4*lhi) =
        pk4(oacc[dt][nt][0], oacc[dt][nt][1], oacc[dt][nt][2], oacc[dt][nt][3]);
  __syncthreads();   // (3) o complete

  // ---- final^T = Wp * o^T ; wave -> (half, c-tile pair) ----
  const int ph = h & 1;
  const int cp = h >> 1;          // 0..2
  f32x4 facc[2][4];
  #pragma unroll
  for (int cc = 0; cc < 2; ++cc)
    #pragma unroll
    for (int nt = 0; nt < 4; ++nt) facc[cc][nt] = zf;
  #pragma unroll
  for (int ks = 0; ks < 6; ++ks) {
    half4v of[4];
    #pragma unroll
    for (int nt = 0; nt < 4; ++nt)
      of[nt] = *(const half4v*)(xo + (16*nt+llo)*200 + 96*ph + 16*ks + 4*lhi);
    #pragma unroll
    for (int cc = 0; cc < 2; ++cc) {
      half4v wp = *(const half4v*)(ws + (size_t)(((6+ph)*6 + 2*cp+cc)*6 + ks)*512 + lane*8);
      #pragma unroll
      for (int nt = 0; nt < 4; ++nt)
        facc[cc][nt] = __builtin_amdgcn_mfma_f32_16x16x16f16(wp, of[nt], facc[cc][nt], 0,0,0);
    }
  }
  const float* pbp = ph ? p2b : p1b;
  float* og = out + (size_t)b * (NT*DM);
  #pragma unroll
  for (int cc = 0; cc < 2; ++cc) {
    float4v pb = *(const float4v*)(pbp + 16*(2*cp+cc) + 4*lhi);
    #pragma unroll
    for (int nt = 0; nt < 4; ++nt) {
      float4v res;
      #pragma unroll
      for (int r = 0; r < 4; ++r) res[r] = facc[cc][nt][r] + pb[r];
      *(float4v*)(og + (size_t)(16*nt+llo)*192 + 96*ph + 16*(2*cp+cc) + 4*lhi) = res;
    }
  }
}

extern "C" void kernel_launch(void* const* d_in, const int* in_sizes, int n_in,
                              void* d_out, int out_size, void* d_ws, size_t ws_size,
                              hipStream_t stream)
{
  const float* x    = (const float*)d_in[0];
  const float* mask = (const float*)d_in[1];
  const float* ls   = (const float*)d_in[2];
  const float* w1   = (const float*)d_in[3];
  const float* b1   = (const float*)d_in[4];
  const float* w2   = (const float*)d_in[5];
  const float* q1w  = (const float*)d_in[6];  const float* q1b = (const float*)d_in[7];
  const float* q2w  = (const float*)d_in[8];  const float* q2b = (const float*)d_in[9];
  const float* k1w  = (const float*)d_in[10]; const float* k1b = (const float*)d_in[11];
  const float* k2w  = (const float*)d_in[12]; const float* k2b = (const float*)d_in[13];
  const float* v1w  = (const float*)d_in[14]; const float* v1b = (const float*)d_in[15];
  const float* v2w  = (const float*)d_in[16]; const float* v2b = (const float*)d_in[17];
  const float* p1w  = (const float*)d_in[18]; const float* p1b = (const float*)d_in[19];
  const float* p2w  = (const float*)d_in[20]; const float* p2b = (const float*)d_in[21];
  const float* rpbt = (const float*)d_in[22];
  const int*   rpi  = (const int*)d_in[23];
  char* ws = (char*)d_ws;
  float* o = (float*)d_out;

  pre_a<<<49, 384, 0, stream>>>(q1w,q2w,k1w,k2w,v1w,v2w,p1w,p2w, w1,b1,w2, rpbt, ls, ws);
  pre_b<<<384, 256, 0, stream>>>(mask, rpi, ws);
  win_attn<<<4096, 384, 0, stream>>>(x, ws, q1b,q2b,k1b,k2b,v1b,v2b,p1b,p2b, o);
}

// Round 10
// 234.406 us; speedup vs baseline: 1.2681x; 1.2681x over previous
//
#include <hip/hip_runtime.h>
#include <hip/hip_bf16.h>

#define NT 64
#define DM 192

typedef __attribute__((ext_vector_type(4))) float f32x4;
typedef __attribute__((ext_vector_type(4))) float float4v;
using half2v = __attribute__((ext_vector_type(2))) _Float16;
using half4v = __attribute__((ext_vector_type(4))) _Float16;

// ws layout (bytes)
#define BIAS_OFF  147456      // 8*36*512 W-frags
#define TAB_OFF   6438912     // BIAS_OFF + 384*16*64*16
#define SCALE_OFF 6444312

__device__ __forceinline__ half4v pk4(float a, float b, float c, float d){
  half2v lo = __builtin_bit_cast(half2v, __builtin_amdgcn_cvt_pkrtz(a, b));
  half2v hi = __builtin_bit_cast(half2v, __builtin_amdgcn_cvt_pkrtz(c, d));
  half4v r; r[0]=lo[0]; r[1]=lo[1]; r[2]=hi[0]; r[3]=hi[1];
  return r;
}

// ---------------- precompute A: W A-frags (16x16x16 layout) + rpb-mlp table + scales ----------------
// Residual fold: q/k/v weights (mats 0..5) get +I so q = x0*(W+I)^T + b  (p-weights unchanged).
__global__ __launch_bounds__(384) void pre_a(
  const float* __restrict__ q1w, const float* __restrict__ q2w,
  const float* __restrict__ k1w, const float* __restrict__ k2w,
  const float* __restrict__ v1w, const float* __restrict__ v2w,
  const float* __restrict__ p1w, const float* __restrict__ p2w,
  const float* __restrict__ w1, const float* __restrict__ b1,
  const float* __restrict__ w2, const float* __restrict__ rpbt,
  const float* __restrict__ ls, char* __restrict__ ws)
{
  int blk = blockIdx.x, t = threadIdx.x;
  if (blk < 48) {
    const float* Ws[8] = {q1w,q2w,k1w,k2w,v1w,v2w,p1w,p2w};
    int mat = blk / 6, ct = blk % 6;
    int lane = t & 63, ks = t >> 6;        // ks 0..5
    const float* W = Ws[mat];
    int c  = 16*ct + (lane & 15);
    int d0 = 16*ks + 4*(lane >> 4);
    half4v h;
    #pragma unroll
    for (int j = 0; j < 4; ++j) {
      float wel = W[c*96 + d0 + j];
      if (mat < 6 && c == d0 + j) wel += 1.0f;   // fold residual identity
      h[j] = (_Float16)wel;
    }
    *(half4v*)(ws + (size_t)((mat*6+ct)*6+ks)*512 + lane*8) = h;
  } else {
    float* tab = (float*)(ws + TAB_OFF);
    if (t < 225) {
      float t0 = rpbt[2*t], t1 = rpbt[2*t+1];
      float acc[6] = {0,0,0,0,0,0};
      for (int j = 0; j < 128; ++j) {
        float hv = fmaxf(t0*w1[2*j] + t1*w1[2*j+1] + b1[j], 0.f);
        #pragma unroll
        for (int hh = 0; hh < 6; ++hh) acc[hh] += hv * w2[hh*128 + j];
      }
      #pragma unroll
      for (int hh = 0; hh < 6; ++hh) tab[t*6 + hh] = acc[hh];
    }
    if (t >= 240 && t < 246) {
      float* sc = (float*)(ws + SCALE_OFF);
      int i = t - 240;
      sc[i] = expf(fminf(ls[i], 4.605170185988091f)); // log(100)
    }
  }
}

// ---------------- precompute B: bias = 16*sigmoid(rpb)+mask in S^T fragment order ----------------
__global__ __launch_bounds__(256) void pre_b(
  const float* __restrict__ mask, const int* __restrict__ rpi,
  char* __restrict__ ws)
{
  int w = blockIdx.x / 6, h = blockIdx.x % 6;
  int lane = threadIdx.x & 63, nt = threadIdx.x >> 6;
  const float* tab = (const float*)(ws + TAB_OFF);
  float* bias = (float*)(ws + BIAS_OFF);
  #pragma unroll
  for (int mt = 0; mt < 4; ++mt)
    #pragma unroll
    for (int r = 0; r < 4; ++r) {
      int m = 16*mt + ((lane >> 4) << 2) + r;
      int n = 16*nt + (lane & 15);
      int idx = rpi[n*64 + m];
      float tv = tab[idx*6 + h];
      float sg = 16.f / (1.f + expf(-tv));
      float mv = mask[(w*64 + n)*64 + m];
      bias[(size_t)(((w*6+h)*4+mt)*4+nt)*256 + lane*4 + r] = sg + mv;
    }
}

// ---------------- main fused kernel: 1 block = 2 windows, 12 waves = 2 x (6 heads) ----------------
// r8 structure + residual folded into weights (no residual reads, no scalar v-gather)
// + deferred softmax normalization (P unnormalized, inv folded into o-store).
__global__ __launch_bounds__(768, 2) void win_attn(
  const float* __restrict__ x, const char* __restrict__ ws,
  const float* __restrict__ q1b, const float* __restrict__ q2b,
  const float* __restrict__ k1b, const float* __restrict__ k2b,
  const float* __restrict__ v1b, const float* __restrict__ v2b,
  const float* __restrict__ p1b, const float* __restrict__ p2b,
  float* __restrict__ out)
{
  __shared__ __align__(16) _Float16 xo2[2][64*200];   // per-window x (f16), later o overlay
  const int tid = threadIdx.x;
  const int wv = tid >> 6, lane = tid & 63;
  const int llo = lane & 15, lhi = lane >> 4;
  const int wgrp = (wv >= 6) ? 1 : 0;   // which window in this block
  const int h = wv - 6*wgrp;            // head 0..5
  const int b = blockIdx.x*2 + wgrp, w_in = b & 63;
  const int lt = tid - 384*wgrp;        // thread id within window group (0..383)
  _Float16* xo = xo2[wgrp];
  const int half = (h < 3) ? 0 : 1;
  const int hd0 = 32 * (h % 3);                   // head-dim base within half
  const f32x4 zf = {0.f,0.f,0.f,0.f};
  const float* xg = x + (size_t)b * (NT*DM);

  // ---- stage x -> LDS f16 (coalesced float4 loads, packed cvt, 8B stores) ----
  float4v xv[8];
  #pragma unroll
  for (int it = 0; it < 8; ++it) xv[it] = *(const float4v*)(xg + 4*(lt + it*384));
  #pragma unroll
  for (int it = 0; it < 8; ++it) {
    int f4 = lt + it*384;
    int row = f4 / 48, c4 = f4 % 48;
    *(half4v*)(xo + row*200 + c4*4) = pk4(xv[it][0], xv[it][1], xv[it][2], xv[it][3]);
  }
  __syncthreads();   // (1) x staged

  const float scale_h = ((const float*)(ws + SCALE_OFF))[h];

  // ---- joint QK pass: q^T,k^T = W' * x^T (+bias), l2norm -> qf/kf frags (residual folded) ----
  half4v qf[2][4], kf[2][4];
  {
    f32x4 qacc[2][4], kacc[2][4];
    #pragma unroll
    for (int dt = 0; dt < 2; ++dt)
      #pragma unroll
      for (int tt = 0; tt < 4; ++tt) { qacc[dt][tt] = zf; kacc[dt][tt] = zf; }
    #pragma unroll
    for (int ks = 0; ks < 6; ++ks) {
      half4v xf[4];
      #pragma unroll
      for (int tt = 0; tt < 4; ++tt)
        xf[tt] = *(const half4v*)(xo + (16*tt+llo)*200 + half*96 + 16*ks + 4*lhi);
      #pragma unroll
      for (int dt = 0; dt < 2; ++dt) {
        half4v wq = *(const half4v*)(ws + (size_t)(((0+half)*6 + 2*(h%3)+dt)*6 + ks)*512 + lane*8);
        half4v wk = *(const half4v*)(ws + (size_t)(((2+half)*6 + 2*(h%3)+dt)*6 + ks)*512 + lane*8);
        #pragma unroll
        for (int tt = 0; tt < 4; ++tt) {
          qacc[dt][tt] = __builtin_amdgcn_mfma_f32_16x16x16f16(wq, xf[tt], qacc[dt][tt], 0,0,0);
          kacc[dt][tt] = __builtin_amdgcn_mfma_f32_16x16x16f16(wk, xf[tt], kacc[dt][tt], 0,0,0);
        }
      }
    }
    const float* qbp = half ? q2b : q1b;
    const float* kbp = half ? k2b : k1b;
    float4v qb[2], kb[2];
    #pragma unroll
    for (int dt = 0; dt < 2; ++dt) {
      qb[dt] = *(const float4v*)(qbp + hd0 + 16*dt + 4*lhi);
      kb[dt] = *(const float4v*)(kbp + hd0 + 16*dt + 4*lhi);
    }
    #pragma unroll
    for (int tt = 0; tt < 4; ++tt) {
      float qv[2][4], kv[2][4];
      float sq = 0.f, sk = 0.f;
      #pragma unroll
      for (int dt = 0; dt < 2; ++dt)
        #pragma unroll
        for (int r = 0; r < 4; ++r) {
          qv[dt][r] = qacc[dt][tt][r] + qb[dt][r]; sq += qv[dt][r]*qv[dt][r];
          kv[dt][r] = kacc[dt][tt][r] + kb[dt][r]; sk += kv[dt][r]*kv[dt][r];
        }
      sq += __shfl_xor(sq, 16); sq += __shfl_xor(sq, 32);
      sk += __shfl_xor(sk, 16); sk += __shfl_xor(sk, 32);
      float invq = scale_h / fmaxf(sqrtf(sq), 1e-12f);   // fold logit scale into qn
      float invk = 1.f / fmaxf(sqrtf(sk), 1e-12f);
      #pragma unroll
      for (int dt = 0; dt < 2; ++dt) {
        qf[dt][tt] = pk4(qv[dt][0]*invq, qv[dt][1]*invq, qv[dt][2]*invq, qv[dt][3]*invq);
        kf[dt][tt] = pk4(kv[dt][0]*invk, kv[dt][1]*invk, kv[dt][2]*invk, kv[dt][3]*invk);
      }
    }
  }

  // ---- S^T = kn * qn^T (+fused bias), softmax over m (in-lane + 2 shfl) -> P^T frags (unnormalized) ----
  const float4v* biasf = (const float4v*)(ws + BIAS_OFF);
  half4v pf[4][4];
  float inv_s[4];
  #pragma unroll
  for (int nt = 0; nt < 4; ++nt) {
    f32x4 s[4];
    #pragma unroll
    for (int mt = 0; mt < 4; ++mt) {
      f32x4 t0 = __builtin_amdgcn_mfma_f32_16x16x16f16(kf[0][mt], qf[0][nt], zf, 0,0,0);
      s[mt]    = __builtin_amdgcn_mfma_f32_16x16x16f16(kf[1][mt], qf[1][nt], t0, 0,0,0);
      float4v bb = biasf[(size_t)(((w_in*6 + h)*4 + mt)*4 + nt)*64 + lane];
      s[mt][0] += bb[0]; s[mt][1] += bb[1]; s[mt][2] += bb[2]; s[mt][3] += bb[3];
    }
    float mx = s[0][0];
    #pragma unroll
    for (int mt = 0; mt < 4; ++mt)
      #pragma unroll
      for (int r = 0; r < 4; ++r) mx = fmaxf(mx, s[mt][r]);
    mx = fmaxf(mx, __shfl_xor(mx, 16)); mx = fmaxf(mx, __shfl_xor(mx, 32));
    float e[4][4]; float sum = 0.f;
    #pragma unroll
    for (int mt = 0; mt < 4; ++mt)
      #pragma unroll
      for (int r = 0; r < 4; ++r) { e[mt][r] = __expf(s[mt][r] - mx); sum += e[mt][r]; }
    sum += __shfl_xor(sum, 16); sum += __shfl_xor(sum, 32);
    inv_s[nt] = 1.f / sum;
    #pragma unroll
    for (int mt = 0; mt < 4; ++mt)
      pf[mt][nt] = pk4(e[mt][0], e[mt][1], e[mt][2], e[mt][3]);
  }

  // ---- V pass: v = x * Wv'^T (+bias) -> vf frags (residual folded into Wv') ----
  half4v vf[4][2];
  {
    f32x4 acc[4][2];
    #pragma unroll
    for (int tt = 0; tt < 4; ++tt) { acc[tt][0] = zf; acc[tt][1] = zf; }
    #pragma unroll
    for (int ks = 0; ks < 6; ++ks) {
      half4v xf[4];
      #pragma unroll
      for (int tt = 0; tt < 4; ++tt)
        xf[tt] = *(const half4v*)(xo + (16*tt+llo)*200 + half*96 + 16*ks + 4*lhi);
      #pragma unroll
      for (int ct = 0; ct < 2; ++ct) {
        half4v wvf = *(const half4v*)(ws + (size_t)(((4+half)*6 + 2*(h%3)+ct)*6 + ks)*512 + lane*8);
        #pragma unroll
        for (int tt = 0; tt < 4; ++tt)
          acc[tt][ct] = __builtin_amdgcn_mfma_f32_16x16x16f16(xf[tt], wvf, acc[tt][ct], 0,0,0);
      }
    }
    const float* vbp = half ? v2b : v1b;
    #pragma unroll
    for (int ct = 0; ct < 2; ++ct) {
      float vb = vbp[hd0 + 16*ct + llo];
      #pragma unroll
      for (int tt = 0; tt < 4; ++tt)
        vf[tt][ct] = pk4(acc[tt][ct][0] + vb, acc[tt][ct][1] + vb,
                         acc[tt][ct][2] + vb, acc[tt][ct][3] + vb);
    }
  }

  // ---- o^T = V^T * P^T (all-register), normalize at store ----
  f32x4 oacc[2][4];
  #pragma unroll
  for (int dt = 0; dt < 2; ++dt)
    #pragma unroll
    for (int nt = 0; nt < 4; ++nt) oacc[dt][nt] = zf;
  #pragma unroll
  for (int mt = 0; mt < 4; ++mt)
    #pragma unroll
    for (int dt = 0; dt < 2; ++dt)
      #pragma unroll
      for (int nt = 0; nt < 4; ++nt)
        oacc[dt][nt] = __builtin_amdgcn_mfma_f32_16x16x16f16(vf[mt][dt], pf[mt][nt], oacc[dt][nt], 0,0,0);

  __syncthreads();   // (2) all waves done reading x
  #pragma unroll
  for (int dt = 0; dt < 2; ++dt)
    #pragma unroll
    for (int nt = 0; nt < 4; ++nt)
      *(half4v*)(xo + (16*nt+llo)*200 + 32*h + 16*dt + 4*lhi) =
        pk4(oacc[dt][nt][0]*inv_s[nt], oacc[dt][nt][1]*inv_s[nt],
            oacc[dt][nt][2]*inv_s[nt], oacc[dt][nt][3]*inv_s[nt]);
  __syncthreads();   // (3) o complete

  // ---- final^T = Wp * o^T ; wave -> (half, c-tile pair) ----
  const int ph = h & 1;
  const int cp = h >> 1;          // 0..2
  f32x4 facc[2][4];
  #pragma unroll
  for (int cc = 0; cc < 2; ++cc)
    #pragma unroll
    for (int nt = 0; nt < 4; ++nt) facc[cc][nt] = zf;
  #pragma unroll
  for (int ks = 0; ks < 6; ++ks) {
    half4v of[4];
    #pragma unroll
    for (int nt = 0; nt < 4; ++nt)
      of[nt] = *(const half4v*)(xo + (16*nt+llo)*200 + 96*ph + 16*ks + 4*lhi);
    #pragma unroll
    for (int cc = 0; cc < 2; ++cc) {
      half4v wp = *(const half4v*)(ws + (size_t)(((6+ph)*6 + 2*cp+cc)*6 + ks)*512 + lane*8);
      #pragma unroll
      for (int nt = 0; nt < 4; ++nt)
        facc[cc][nt] = __builtin_amdgcn_mfma_f32_16x16x16f16(wp, of[nt], facc[cc][nt], 0,0,0);
    }
  }
  const float* pbp = ph ? p2b : p1b;
  float* og = out + (size_t)b * (NT*DM);
  #pragma unroll
  for (int cc = 0; cc < 2; ++cc) {
    float4v pb = *(const float4v*)(pbp + 16*(2*cp+cc) + 4*lhi);
    #pragma unroll
    for (int nt = 0; nt < 4; ++nt) {
      float4v res;
      #pragma unroll
      for (int r = 0; r < 4; ++r) res[r] = facc[cc][nt][r] + pb[r];
      *(float4v*)(og + (size_t)(16*nt+llo)*192 + 96*ph + 16*(2*cp+cc) + 4*lhi) = res;
    }
  }
}

extern "C" void kernel_launch(void* const* d_in, const int* in_sizes, int n_in,
                              void* d_out, int out_size, void* d_ws, size_t ws_size,
                              hipStream_t stream)
{
  const float* x    = (const float*)d_in[0];
  const float* mask = (const float*)d_in[1];
  const float* ls   = (const float*)d_in[2];
  const float* w1   = (const float*)d_in[3];
  const float* b1   = (const float*)d_in[4];
  const float* w2   = (const float*)d_in[5];
  const float* q1w  = (const float*)d_in[6];  const float* q1b = (const float*)d_in[7];
  const float* q2w  = (const float*)d_in[8];  const float* q2b = (const float*)d_in[9];
  const float* k1w  = (const float*)d_in[10]; const float* k1b = (const float*)d_in[11];
  const float* k2w  = (const float*)d_in[12]; const float* k2b = (const float*)d_in[13];
  const float* v1w  = (const float*)d_in[14]; const float* v1b = (const float*)d_in[15];
  const float* v2w  = (const float*)d_in[16]; const float* v2b = (const float*)d_in[17];
  const float* p1w  = (const float*)d_in[18]; const float* p1b = (const float*)d_in[19];
  const float* p2w  = (const float*)d_in[20]; const float* p2b = (const float*)d_in[21];
  const float* rpbt = (const float*)d_in[22];
  const int*   rpi  = (const int*)d_in[23];
  char* ws = (char*)d_ws;
  float* o = (float*)d_out;

  pre_a<<<49, 384, 0, stream>>>(q1w,q2w,k1w,k2w,v1w,v2w,p1w,p2w, w1,b1,w2, rpbt, ls, ws);
  pre_b<<<384, 256, 0, stream>>>(mask, rpi, ws);
  win_attn<<<2048, 768, 0, stream>>>(x, ws, q1b,q2b,k1b,k2b,v1b,v2b,p1b,p2b, o);
}

// Round 11
// 221.058 us; speedup vs baseline: 1.3447x; 1.0604x over previous
//
#include <hip/hip_runtime.h>
#include <hip/hip_bf16.h>

#define NT 64
#define DM 192

typedef __attribute__((ext_vector_type(4))) float f32x4;
typedef __attribute__((ext_vector_type(4))) float float4v;
using half2v = __attribute__((ext_vector_type(2))) _Float16;
using half4v = __attribute__((ext_vector_type(4))) _Float16;
using half8v = __attribute__((ext_vector_type(8))) _Float16;

// ws layout (bytes)
#define BIAS_OFF  147456      // 8*6*3*1024 W-frags
#define TAB_OFF   6438912     // BIAS_OFF + 384*16*64*16
#define SCALE_OFF 6444312

__device__ __forceinline__ half4v pk4(float a, float b, float c, float d){
  half2v lo = __builtin_bit_cast(half2v, __builtin_amdgcn_cvt_pkrtz(a, b));
  half2v hi = __builtin_bit_cast(half2v, __builtin_amdgcn_cvt_pkrtz(c, d));
  half4v r; r[0]=lo[0]; r[1]=lo[1]; r[2]=hi[0]; r[3]=hi[1];
  return r;
}

// ---------------- precompute A: W frags in 16x16x32 layout + rpb-mlp table + scales ----------------
// frag(mat, ct, ks): lane holds W'[16ct + (lane&15)][32ks + 8*(lane>>4) + j], j=0..7 (f16).
// Same lane map serves A-orientation (row=llo) and B-orientation (col=llo).
// Residual fold: q/k/v weights (mats 0..5) get +I.
__global__ __launch_bounds__(384) void pre_a(
  const float* __restrict__ q1w, const float* __restrict__ q2w,
  const float* __restrict__ k1w, const float* __restrict__ k2w,
  const float* __restrict__ v1w, const float* __restrict__ v2w,
  const float* __restrict__ p1w, const float* __restrict__ p2w,
  const float* __restrict__ w1, const float* __restrict__ b1,
  const float* __restrict__ w2, const float* __restrict__ rpbt,
  const float* __restrict__ ls, char* __restrict__ ws)
{
  int blk = blockIdx.x, t = threadIdx.x;
  if (blk < 48) {
    const float* Ws[8] = {q1w,q2w,k1w,k2w,v1w,v2w,p1w,p2w};
    int mat = blk / 6, ct = blk % 6;
    int lane = t & 63, ks = t >> 6;        // ks 0..5, only 0..2 used
    if (ks < 3) {
      const float* W = Ws[mat];
      int c  = 16*ct + (lane & 15);
      int d0 = 32*ks + 8*(lane >> 4);
      half8v h;
      #pragma unroll
      for (int j = 0; j < 8; ++j) {
        float wel = W[c*96 + d0 + j];
        if (mat < 6 && c == d0 + j) wel += 1.0f;   // fold residual identity
        h[j] = (_Float16)wel;
      }
      *(half8v*)(ws + (size_t)((mat*6+ct)*3+ks)*1024 + lane*16) = h;
    }
  } else {
    float* tab = (float*)(ws + TAB_OFF);
    if (t < 225) {
      float t0 = rpbt[2*t], t1 = rpbt[2*t+1];
      float acc[6] = {0,0,0,0,0,0};
      for (int j = 0; j < 128; ++j) {
        float hv = fmaxf(t0*w1[2*j] + t1*w1[2*j+1] + b1[j], 0.f);
        #pragma unroll
        for (int hh = 0; hh < 6; ++hh) acc[hh] += hv * w2[hh*128 + j];
      }
      #pragma unroll
      for (int hh = 0; hh < 6; ++hh) tab[t*6 + hh] = acc[hh];
    }
    if (t >= 240 && t < 246) {
      float* sc = (float*)(ws + SCALE_OFF);
      int i = t - 240;
      sc[i] = expf(fminf(ls[i], 4.605170185988091f)); // log(100)
    }
  }
}

// ---------------- precompute B: bias = 16*sigmoid(rpb)+mask in S^T fragment order ----------------
__global__ __launch_bounds__(256) void pre_b(
  const float* __restrict__ mask, const int* __restrict__ rpi,
  char* __restrict__ ws)
{
  int w = blockIdx.x / 6, h = blockIdx.x % 6;
  int lane = threadIdx.x & 63, nt = threadIdx.x >> 6;
  const float* tab = (const float*)(ws + TAB_OFF);
  float* bias = (float*)(ws + BIAS_OFF);
  #pragma unroll
  for (int mt = 0; mt < 4; ++mt)
    #pragma unroll
    for (int r = 0; r < 4; ++r) {
      int m = 16*mt + ((lane >> 4) << 2) + r;
      int n = 16*nt + (lane & 15);
      int idx = rpi[n*64 + m];
      float tv = tab[idx*6 + h];
      float sg = 16.f / (1.f + expf(-tv));
      float mv = mask[(w*64 + n)*64 + m];
      bias[(size_t)(((w*6+h)*4+mt)*4+nt)*256 + lane*4 + r] = sg + mv;
    }
}

// ---------------- main fused kernel: 1 block = 2 windows, 12 waves = 2 x (6 heads) ----------------
// x-consuming GEMMs (QK, V, proj) use 16x16x32_f16 (2xK); S and PV stay 16x16x16 for
// register fragment chaining. Residual folded into weights; deferred softmax normalization.
__global__ __launch_bounds__(768, 2) void win_attn(
  const float* __restrict__ x, const char* __restrict__ ws,
  const float* __restrict__ q1b, const float* __restrict__ q2b,
  const float* __restrict__ k1b, const float* __restrict__ k2b,
  const float* __restrict__ v1b, const float* __restrict__ v2b,
  const float* __restrict__ p1b, const float* __restrict__ p2b,
  float* __restrict__ out)
{
  __shared__ __align__(16) _Float16 xo2[2][64*200];   // per-window x (f16), later o overlay
  const int tid = threadIdx.x;
  const int wv = tid >> 6, lane = tid & 63;
  const int llo = lane & 15, lhi = lane >> 4;
  const int wgrp = (wv >= 6) ? 1 : 0;   // which window in this block
  const int h = wv - 6*wgrp;            // head 0..5
  const int b = blockIdx.x*2 + wgrp, w_in = b & 63;
  const int lt = tid - 384*wgrp;        // thread id within window group (0..383)
  _Float16* xo = xo2[wgrp];
  const int half = (h < 3) ? 0 : 1;
  const int hd0 = 32 * (h % 3);                   // head-dim base within half
  const f32x4 zf = {0.f,0.f,0.f,0.f};
  const float* xg = x + (size_t)b * (NT*DM);

  // ---- stage x -> LDS f16 (coalesced float4 loads, packed cvt, 8B stores) ----
  float4v xv[8];
  #pragma unroll
  for (int it = 0; it < 8; ++it) xv[it] = *(const float4v*)(xg + 4*(lt + it*384));
  #pragma unroll
  for (int it = 0; it < 8; ++it) {
    int f4 = lt + it*384;
    int row = f4 / 48, c4 = f4 % 48;
    *(half4v*)(xo + row*200 + c4*4) = pk4(xv[it][0], xv[it][1], xv[it][2], xv[it][3]);
  }
  __syncthreads();   // (1) x staged

  const float scale_h = ((const float*)(ws + SCALE_OFF))[h];

  // ---- joint QK pass (x32): q^T,k^T = W' * x^T (+bias), l2norm -> qf/kf frags ----
  half4v qf[2][4], kf[2][4];
  {
    f32x4 qacc[2][4], kacc[2][4];
    #pragma unroll
    for (int dt = 0; dt < 2; ++dt)
      #pragma unroll
      for (int tt = 0; tt < 4; ++tt) { qacc[dt][tt] = zf; kacc[dt][tt] = zf; }
    __builtin_amdgcn_s_setprio(1);
    #pragma unroll
    for (int ks = 0; ks < 3; ++ks) {
      half8v xf[4];
      #pragma unroll
      for (int tt = 0; tt < 4; ++tt)
        xf[tt] = *(const half8v*)(xo + (16*tt+llo)*200 + half*96 + 32*ks + 8*lhi);
      #pragma unroll
      for (int dt = 0; dt < 2; ++dt) {
        half8v wq = *(const half8v*)(ws + (size_t)(((0+half)*6 + 2*(h%3)+dt)*3 + ks)*1024 + lane*16);
        half8v wk = *(const half8v*)(ws + (size_t)(((2+half)*6 + 2*(h%3)+dt)*3 + ks)*1024 + lane*16);
        #pragma unroll
        for (int tt = 0; tt < 4; ++tt) {
          qacc[dt][tt] = __builtin_amdgcn_mfma_f32_16x16x32_f16(wq, xf[tt], qacc[dt][tt], 0,0,0);
          kacc[dt][tt] = __builtin_amdgcn_mfma_f32_16x16x32_f16(wk, xf[tt], kacc[dt][tt], 0,0,0);
        }
      }
    }
    __builtin_amdgcn_s_setprio(0);
    const float* qbp = half ? q2b : q1b;
    const float* kbp = half ? k2b : k1b;
    float4v qb[2], kb[2];
    #pragma unroll
    for (int dt = 0; dt < 2; ++dt) {
      qb[dt] = *(const float4v*)(qbp + hd0 + 16*dt + 4*lhi);
      kb[dt] = *(const float4v*)(kbp + hd0 + 16*dt + 4*lhi);
    }
    #pragma unroll
    for (int tt = 0; tt < 4; ++tt) {
      float qv[2][4], kv[2][4];
      float sq = 0.f, sk = 0.f;
      #pragma unroll
      for (int dt = 0; dt < 2; ++dt)
        #pragma unroll
        for (int r = 0; r < 4; ++r) {
          qv[dt][r] = qacc[dt][tt][r] + qb[dt][r]; sq += qv[dt][r]*qv[dt][r];
          kv[dt][r] = kacc[dt][tt][r] + kb[dt][r]; sk += kv[dt][r]*kv[dt][r];
        }
      sq += __shfl_xor(sq, 16); sq += __shfl_xor(sq, 32);
      sk += __shfl_xor(sk, 16); sk += __shfl_xor(sk, 32);
      float invq = scale_h / fmaxf(sqrtf(sq), 1e-12f);   // fold logit scale into qn
      float invk = 1.f / fmaxf(sqrtf(sk), 1e-12f);
      #pragma unroll
      for (int dt = 0; dt < 2; ++dt) {
        qf[dt][tt] = pk4(qv[dt][0]*invq, qv[dt][1]*invq, qv[dt][2]*invq, qv[dt][3]*invq);
        kf[dt][tt] = pk4(kv[dt][0]*invk, kv[dt][1]*invk, kv[dt][2]*invk, kv[dt][3]*invk);
      }
    }
  }

  // ---- S^T = kn * qn^T (x16, +fused bias), softmax over m -> P^T frags (unnormalized) ----
  const float4v* biasf = (const float4v*)(ws + BIAS_OFF);
  half4v pf[4][4];
  float inv_s[4];
  #pragma unroll
  for (int nt = 0; nt < 4; ++nt) {
    f32x4 s[4];
    #pragma unroll
    for (int mt = 0; mt < 4; ++mt) {
      f32x4 t0 = __builtin_amdgcn_mfma_f32_16x16x16f16(kf[0][mt], qf[0][nt], zf, 0,0,0);
      s[mt]    = __builtin_amdgcn_mfma_f32_16x16x16f16(kf[1][mt], qf[1][nt], t0, 0,0,0);
      float4v bb = biasf[(size_t)(((w_in*6 + h)*4 + mt)*4 + nt)*64 + lane];
      s[mt][0] += bb[0]; s[mt][1] += bb[1]; s[mt][2] += bb[2]; s[mt][3] += bb[3];
    }
    float mx = s[0][0];
    #pragma unroll
    for (int mt = 0; mt < 4; ++mt)
      #pragma unroll
      for (int r = 0; r < 4; ++r) mx = fmaxf(mx, s[mt][r]);
    mx = fmaxf(mx, __shfl_xor(mx, 16)); mx = fmaxf(mx, __shfl_xor(mx, 32));
    float e[4][4]; float sum = 0.f;
    #pragma unroll
    for (int mt = 0; mt < 4; ++mt)
      #pragma unroll
      for (int r = 0; r < 4; ++r) { e[mt][r] = __expf(s[mt][r] - mx); sum += e[mt][r]; }
    sum += __shfl_xor(sum, 16); sum += __shfl_xor(sum, 32);
    inv_s[nt] = 1.f / sum;
    #pragma unroll
    for (int mt = 0; mt < 4; ++mt)
      pf[mt][nt] = pk4(e[mt][0], e[mt][1], e[mt][2], e[mt][3]);
  }

  // ---- V pass (x32): v = x * Wv'^T (+bias) -> vf frags ----
  half4v vf[4][2];
  {
    f32x4 acc[4][2];
    #pragma unroll
    for (int tt = 0; tt < 4; ++tt) { acc[tt][0] = zf; acc[tt][1] = zf; }
    #pragma unroll
    for (int ks = 0; ks < 3; ++ks) {
      half8v xf[4];
      #pragma unroll
      for (int tt = 0; tt < 4; ++tt)
        xf[tt] = *(const half8v*)(xo + (16*tt+llo)*200 + half*96 + 32*ks + 8*lhi);
      #pragma unroll
      for (int ct = 0; ct < 2; ++ct) {
        half8v wvf = *(const half8v*)(ws + (size_t)(((4+half)*6 + 2*(h%3)+ct)*3 + ks)*1024 + lane*16);
        #pragma unroll
        for (int tt = 0; tt < 4; ++tt)
          acc[tt][ct] = __builtin_amdgcn_mfma_f32_16x16x32_f16(xf[tt], wvf, acc[tt][ct], 0,0,0);
      }
    }
    const float* vbp = half ? v2b : v1b;
    #pragma unroll
    for (int ct = 0; ct < 2; ++ct) {
      float vb = vbp[hd0 + 16*ct + llo];
      #pragma unroll
      for (int tt = 0; tt < 4; ++tt)
        vf[tt][ct] = pk4(acc[tt][ct][0] + vb, acc[tt][ct][1] + vb,
                         acc[tt][ct][2] + vb, acc[tt][ct][3] + vb);
    }
  }

  // ---- o^T = V^T * P^T (x16, all-register), normalize at store ----
  f32x4 oacc[2][4];
  #pragma unroll
  for (int dt = 0; dt < 2; ++dt)
    #pragma unroll
    for (int nt = 0; nt < 4; ++nt) oacc[dt][nt] = zf;
  __builtin_amdgcn_s_setprio(1);
  #pragma unroll
  for (int mt = 0; mt < 4; ++mt)
    #pragma unroll
    for (int dt = 0; dt < 2; ++dt)
      #pragma unroll
      for (int nt = 0; nt < 4; ++nt)
        oacc[dt][nt] = __builtin_amdgcn_mfma_f32_16x16x16f16(vf[mt][dt], pf[mt][nt], oacc[dt][nt], 0,0,0);
  __builtin_amdgcn_s_setprio(0);

  __syncthreads();   // (2) all waves done reading x
  #pragma unroll
  for (int dt = 0; dt < 2; ++dt)
    #pragma unroll
    for (int nt = 0; nt < 4; ++nt)
      *(half4v*)(xo + (16*nt+llo)*200 + 32*h + 16*dt + 4*lhi) =
        pk4(oacc[dt][nt][0]*inv_s[nt], oacc[dt][nt][1]*inv_s[nt],
            oacc[dt][nt][2]*inv_s[nt], oacc[dt][nt][3]*inv_s[nt]);
  __syncthreads();   // (3) o complete

  // ---- final^T = Wp * o^T (x32) ; wave -> (half, c-tile pair) ----
  const int ph = h & 1;
  const int cp = h >> 1;          // 0..2
  f32x4 facc[2][4];
  #pragma unroll
  for (int cc = 0; cc < 2; ++cc)
    #pragma unroll
    for (int nt = 0; nt < 4; ++nt) facc[cc][nt] = zf;
  #pragma unroll
  for (int ks = 0; ks < 3; ++ks) {
    half8v of[4];
    #pragma unroll
    for (int nt = 0; nt < 4; ++nt)
      of[nt] = *(const half8v*)(xo + (16*nt+llo)*200 + 96*ph + 32*ks + 8*lhi);
    #pragma unroll
    for (int cc = 0; cc < 2; ++cc) {
      half8v wp = *(const half8v*)(ws + (size_t)(((6+ph)*6 + 2*cp+cc)*3 + ks)*1024 + lane*16);
      #pragma unroll
      for (int nt = 0; nt < 4; ++nt)
        facc[cc][nt] = __builtin_amdgcn_mfma_f32_16x16x32_f16(wp, of[nt], facc[cc][nt], 0,0,0);
    }
  }
  const float* pbp = ph ? p2b : p1b;
  float* og = out + (size_t)b * (NT*DM);
  #pragma unroll
  for (int cc = 0; cc < 2; ++cc) {
    float4v pb = *(const float4v*)(pbp + 16*(2*cp+cc) + 4*lhi);
    #pragma unroll
    for (int nt = 0; nt < 4; ++nt) {
      float4v res;
      #pragma unroll
      for (int r = 0; r < 4; ++r) res[r] = facc[cc][nt][r] + pb[r];
      *(float4v*)(og + (size_t)(16*nt+llo)*192 + 96*ph + 16*(2*cp+cc) + 4*lhi) = res;
    }
  }
}

extern "C" void kernel_launch(void* const* d_in, const int* in_sizes, int n_in,
                              void* d_out, int out_size, void* d_ws, size_t ws_size,
                              hipStream_t stream)
{
  const float* x    = (const float*)d_in[0];
  const float* mask = (const float*)d_in[1];
  const float* ls   = (const float*)d_in[2];
  const float* w1   = (const float*)d_in[3];
  const float* b1   = (const float*)d_in[4];
  const float* w2   = (const float*)d_in[5];
  const float* q1w  = (const float*)d_in[6];  const float* q1b = (const float*)d_in[7];
  const float* q2w  = (const float*)d_in[8];  const float* q2b = (const float*)d_in[9];
  const float* k1w  = (const float*)d_in[10]; const float* k1b = (const float*)d_in[11];
  const float* k2w  = (const float*)d_in[12]; const float* k2b = (const float*)d_in[13];
  const float* v1w  = (const float*)d_in[14]; const float* v1b = (const float*)d_in[15];
  const float* v2w  = (const float*)d_in[16]; const float* v2b = (const float*)d_in[17];
  const float* p1w  = (const float*)d_in[18]; const float* p1b = (const float*)d_in[19];
  const float* p2w  = (const float*)d_in[20]; const float* p2b = (const float*)d_in[21];
  const float* rpbt = (const float*)d_in[22];
  const int*   rpi  = (const int*)d_in[23];
  char* ws = (char*)d_ws;
  float* o = (float*)d_out;

  pre_a<<<49, 384, 0, stream>>>(q1w,q2w,k1w,k2w,v1w,v2w,p1w,p2w, w1,b1,w2, rpbt, ls, ws);
  pre_b<<<384, 256, 0, stream>>>(mask, rpi, ws);
  win_attn<<<2048, 768, 0, stream>>>(x, ws, q1b,q2b,k1b,k2b,v1b,v2b,p1b,p2b, o);
}